// Round 4
// baseline (218.024 us; speedup 1.0000x reference)
//
#include <hip/hip_runtime.h>
#include <hip/hip_fp16.h>
#include <hip/hip_cooperative_groups.h>

namespace cg = cooperative_groups;

// SE3 divergence-free vector field — fused single-dispatch, v4.1.
//
// curl = (psi2-psi1, psi0-psi2, psi1-psi0) = (A, B, -A-B).
// Tabulate per u the two difference profiles q0=psi2-psi1, q1=psi0-psi2 with
// wcut/(8*sqrt8) folded in.  Table row: 16 half2 (64 B), entry t=2u+q holds
// (q_t(r_i), q_t(r_{i+1})) so one row gives both lerp endpoints.
//
// ONE cooperative dispatch:
//   phase A: zero out[] (grid-stride) + blocks 0..63 build the table
//   grid.sync()
//   phase B: one edge per thread, 3 fire-and-forget HW fp32 atomics into out
// Fallback (if cooperative launch unavailable under capture): same phases as
// two plain dispatches.

#define THREADS 256
#define RTAB 2048
#define ROWH 32                          // halves per row -> 64 B stride
#define TBLOCKS ((RTAB * 8) / THREADS)   // 64 blocks of table entries

// ---------- shared device helpers ----------

__device__ __forceinline__ void stage_weights(const float* __restrict__ W1,
                                              const float* __restrict__ W2,
                                              float* sW1, float* sDW2) {
    for (int t = threadIdx.x; t < 640; t += THREADS) {
        int j = t >> 6, k = t & 63;
        sW1[j * 65 + k] = W1[t];
    }
    // difference weights: [k][2u+0] = W2c(u,2)-W2c(u,1), [k][2u+1] = W2c(u,0)-W2c(u,2)
    for (int t = threadIdx.x; t < 64 * 16; t += THREADS) {
        int k = t >> 4, j = t & 15;
        int u = j >> 1;
        const float* w2 = W2 + k * 384 + u * 32;
        sDW2[t] = (j & 1) ? (w2[0] - w2[2]) : (w2[2] - w2[1]);
    }
}

__device__ __forceinline__ void table_entry(int g, const float* sW1,
                                            const float* sDW2,
                                            __half* __restrict__ T) {
    int i = g >> 3;       // table row
    int u = g & 7;        // input feature

    float r = 3.0f * (float)i / (float)(RTAB - 1);
    float q0 = 0.f, q1 = 0.f;
    float t10 = 10.0f - (10.0f / 3.0f) * r;
    if (t10 > 0.0f) {
        // radial bump embedding: at most 2 of 10 basis functions non-zero.
        const float C0 = 8.43357306907549f;   // 1.14136*e^2 (sqrt10 cancels)
        float q  = r * (11.0f / 3.0f);
        int   jf = (int)q;
        float da = q - (float)jf;
        float db = da - 1.0f;
        float ya = fmaxf(1.0f - da * da, 1e-7f);
        float yb = fmaxf(1.0f - db * db, 1e-7f);
        int ja = jf - 1, jb = jf;
        float ea = (ja >= 0) ? C0 * __expf(-1.0f / ya) : 0.0f;
        float eb = (jb <= 9) ? C0 * __expf(-1.0f / yb) : 0.0f;
        int jac = ja < 0 ? 0 : ja;
        int jbc = jb > 9 ? 9 : jb;
        const float* w1a = sW1 + jac * 65;
        const float* w1b = sW1 + jbc * 65;
        const float* dw  = sDW2 + 2 * u;

        float a0 = 0.f, a1 = 0.f;
#pragma unroll 8
        for (int k = 0; k < 64; ++k) {
            float pre = ea * w1a[k] + eb * w1b[k];
            float h   = pre * __builtin_amdgcn_rcpf(1.0f + __expf(-pre)); // silu
            a0 = fmaf(h, dw[16 * k + 0], a0);
            a1 = fmaf(h, dw[16 * k + 1], a1);
        }
        float sc = __expf(-1.0f / t10) * 0.04419417382415922f; // wcut/(8*sqrt8)
        q0 = a0 * sc;
        q1 = a1 * sc;
    }

    __half h0 = __float2half(q0);
    __half h1 = __float2half(q1);
    size_t base = (size_t)i * ROWH + 4 * u;
    T[base + 0] = h0;                       // row i, q0 .x endpoint
    T[base + 2] = h1;                       // row i, q1 .x endpoint
    if (i > 0) {
        T[base - ROWH + 1] = h0;            // row i-1, q0 .y endpoint
        T[base - ROWH + 3] = h1;            // row i-1, q1 .y endpoint
    }
    if (i == RTAB - 1) {                    // defensive: clear unused .y slots
        T[base + 1] = h0;
        T[base + 3] = h1;
    }
}

__device__ __forceinline__ void edge_work(int e,
    const float* __restrict__ x, const float* __restrict__ pos,
    const int* __restrict__ esrc, const int* __restrict__ edst,
    const __half* __restrict__ T, float* __restrict__ out)
{
    int s = esrc[e];
    int d = edst[e];

    float ex = pos[3 * s + 0] - pos[3 * d + 0];
    float ey = pos[3 * s + 1] - pos[3 * d + 1];
    float ez = pos[3 * s + 2] - pos[3 * d + 2];
    float r  = sqrtf(ex * ex + ey * ey + ez * ez + 1e-18f);

    if (r >= 3.0f) return;   // wcut == 0 -> edge contributes nothing

    float tq = r * ((float)(RTAB - 1) / 3.0f);
    int   i  = (int)tq;
    if (i > RTAB - 2) i = RTAB - 2;
    float f  = tq - (float)i;

    const float4* rowp = reinterpret_cast<const float4*>(T + (size_t)i * ROWH);
    const float4* xf   = reinterpret_cast<const float4*>(x + 8 * (size_t)s);
    float4 r0 = rowp[0], r1 = rowp[1], r2 = rowp[2], r3 = rowp[3];
    float4 xA = xf[0];
    float4 xB = xf[1];

    float c0 = 0.f, c1 = 0.f;
    // one float4 = entries for u2, u2+1: (q0,q1) each as half2(lo,hi)
    auto proc = [&](float4 v, float xu, float xv) {
        union { float4 f4; __half2 h[4]; } cv; cv.f4 = v;
        float2 a0 = __half22float2(cv.h[0]);
        float2 a1 = __half22float2(cv.h[1]);
        float2 a2 = __half22float2(cv.h[2]);
        float2 a3 = __half22float2(cv.h[3]);
        c0 = fmaf(xu, fmaf(f, a0.y - a0.x, a0.x), c0);
        c1 = fmaf(xu, fmaf(f, a1.y - a1.x, a1.x), c1);
        c0 = fmaf(xv, fmaf(f, a2.y - a2.x, a2.x), c0);
        c1 = fmaf(xv, fmaf(f, a3.y - a3.x, a3.x), c1);
    };
    proc(r0, xA.x, xA.y);
    proc(r1, xA.z, xA.w);
    proc(r2, xB.x, xB.y);
    proc(r3, xB.z, xB.w);

    // fire-and-forget HW fp32 atomics (no return value -> no latency exposure)
    float* ob = out + 3 * (size_t)d;
    unsafeAtomicAdd(ob + 0, c0);
    unsafeAtomicAdd(ob + 1, c1);
    unsafeAtomicAdd(ob + 2, -c0 - c1);
}

// ---------- fused cooperative kernel ----------

__global__ __launch_bounds__(THREADS) void se3_fused(
    const float* __restrict__ x, const float* __restrict__ pos,
    const int* __restrict__ esrc, const int* __restrict__ edst,
    const float* __restrict__ W1, const float* __restrict__ W2,
    __half* __restrict__ T, float* __restrict__ out, int E, int outN)
{
    __shared__ float sW1[10 * 65];
    __shared__ float sDW2[64 * 16];

    int tid = blockIdx.x * THREADS + threadIdx.x;
    int nth = gridDim.x * THREADS;

    // phase A: zero the output (grid-stride) ...
    float4 z = make_float4(0.f, 0.f, 0.f, 0.f);
    for (int idx = tid; idx < (outN >> 2); idx += nth)
        reinterpret_cast<float4*>(out)[idx] = z;

    // ... and build the radial table on the first 64 blocks
    if (blockIdx.x < TBLOCKS) {
        stage_weights(W1, W2, sW1, sDW2);
        __syncthreads();
        table_entry(tid, sW1, sDW2, T);   // tid < 16384 here by construction
    }

    cg::this_grid().sync();

    // phase B: edges
    for (int e = tid; e < E; e += nth)
        edge_work(e, x, pos, esrc, edst, T, out);
}

// ---------- split fallback kernels ----------

__global__ __launch_bounds__(THREADS) void se3_build_split(
    const float* __restrict__ W1, const float* __restrict__ W2,
    __half* __restrict__ T, float4* __restrict__ zbuf, int zcount4)
{
    __shared__ float sW1[10 * 65];
    __shared__ float sDW2[64 * 16];

    int g = blockIdx.x * THREADS + threadIdx.x;
    float4 z = make_float4(0.f, 0.f, 0.f, 0.f);
    for (int idx = g; idx < zcount4; idx += gridDim.x * THREADS)
        zbuf[idx] = z;

    stage_weights(W1, W2, sW1, sDW2);
    __syncthreads();
    if (g < RTAB * 8) table_entry(g, sW1, sDW2, T);
}

__global__ __launch_bounds__(THREADS) void se3_edge_split(
    const float* __restrict__ x, const float* __restrict__ pos,
    const int* __restrict__ esrc, const int* __restrict__ edst,
    const __half* __restrict__ T, float* __restrict__ out, int E)
{
    int e = blockIdx.x * THREADS + threadIdx.x;
    if (e < E) edge_work(e, x, pos, esrc, edst, T, out);
}

// ---------- host ----------

extern "C" void kernel_launch(void* const* d_in, const int* in_sizes, int n_in,
                              void* d_out, int out_size, void* d_ws, size_t ws_size,
                              hipStream_t stream) {
    const float* x    = (const float*)d_in[0];
    const float* pos  = (const float*)d_in[1];
    const int*   esrc = (const int*)d_in[2];
    const int*   edst = (const int*)d_in[3];
    const float* W1   = (const float*)d_in[4];
    const float* W2   = (const float*)d_in[5];
    float* out = (float*)d_out;

    int E    = in_sizes[2];
    int outN = out_size;          // B*N*3 floats
    __half* T = (__half*)d_ws;    // 128 KB table in workspace

    // co-residency-safe grid for the cooperative launch
    int blocksPerCU = 0;
    if (hipOccupancyMaxActiveBlocksPerMultiprocessor(
            &blocksPerCU, se3_fused, THREADS, 0) != hipSuccess || blocksPerCU < 1)
        blocksPerCU = 2;   // conservative
    int nCU = 0;
    int dev = 0;
    (void)hipGetDevice(&dev);
    if (hipDeviceGetAttribute(&nCU, hipDeviceAttributeMultiprocessorCount, dev)
            != hipSuccess || nCU < 1)
        nCU = 256;

    long cap  = (long)blocksPerCU * (long)nCU;
    int  grid = (E + THREADS - 1) / THREADS;     // 1 edge per thread if it fits
    if ((long)grid > cap) grid = (int)cap;
    if (grid < TBLOCKS) grid = TBLOCKS;          // table needs >= 64 blocks

    void* args[] = {(void*)&x, (void*)&pos, (void*)&esrc, (void*)&edst,
                    (void*)&W1, (void*)&W2, (void*)&T, (void*)&out,
                    (void*)&E, (void*)&outN};

    hipError_t err = hipLaunchCooperativeKernel(
        se3_fused, dim3(grid), dim3(THREADS), args, 0, stream);

    if (err != hipSuccess) {
        (void)hipGetLastError();   // clear sticky error, use plain dispatches
        se3_build_split<<<TBLOCKS, THREADS, 0, stream>>>(
            W1, W2, T, (float4*)out, outN / 4);
        se3_edge_split<<<(E + THREADS - 1) / THREADS, THREADS, 0, stream>>>(
            x, pos, esrc, edst, T, out, E);
    }
}